// Round 12
// baseline (171.103 us; speedup 1.0000x reference)
//
#include <hip/hip_runtime.h>
#include <math.h>

#define B 256
#define N 1152
#define C_ 10
#define OUT 16
#define IN 8
#define KO 160          // C_*OUT

// ---- shared geometry: 64-thread (1-wave) blocks, BT=4 rows/thread, KG=5 capsules x 2
#define MB 16           // batch rows per block
#define NC 12           // n per chunk
#define NCH 96          // N/NC
#define KG 5
#define XSTR 100        // NC*8+4: padded x row stride

// s[b*160 + k*16 + o] += sum_{n in chunk} c[n,k]*(W[n,k,o,:].x[b,n,:])   (atomic)
// grid 3072 = 8 XCD * 12 chl * 2 kg * 16 bt (bt fastest: 16 blocks share one W chunk
// within the dispatch). No partial slab: R11 lesson — L2 is invalidated across kernel
// boundaries, so the 21MB slab cost 42MB of L2<->L3 traffic per iteration.
__global__ __launch_bounds__(64, 4) void k_s_partial(
    const float* __restrict__ x, const float* __restrict__ W,
    const float* __restrict__ c, float* __restrict__ s)
{
    __shared__ float xs[MB][XSTR];      // 6.25 KB
    __shared__ float cs[NC][KG];

    const int tid = threadIdx.x;
    const int id  = blockIdx.x;
    const int g   = id & 7;             // XCD
    const int q   = id >> 3;            // 0..383
    const int bt  = q & 15;
    const int kg  = (q >> 4) & 1;
    const int chl = q >> 5;             // 0..11
    const int ch  = g * 12 + chl;       // 0..95
    const int b0  = bt * MB;
    const int n0  = ch * NC;
    const int k0  = kg * KG;

    for (int idx = tid; idx < MB * (NC * 2); idx += 64) {   // 16 rows x 24 float4
        int bl = idx / (NC * 2), r = idx - bl * (NC * 2);
        float4 val = *(const float4*)(x + (size_t)(b0 + bl) * (N * IN) + (size_t)n0 * IN + r * 4);
        *(float4*)(&xs[bl][r * 4]) = val;
    }
    if (c) {
        for (int idx = tid; idx < NC * KG; idx += 64) {
            int nl = idx / KG, kk = idx - nl * KG;
            cs[nl][kk] = c[(size_t)(n0 + nl) * C_ + (k0 + kk)];
        }
    }
    __syncthreads();

    const int o   = tid & 15;
    const int grp = (tid >> 4) * 4;

    float acc[4][KG];
#pragma unroll
    for (int r = 0; r < 4; ++r)
#pragma unroll
        for (int kk = 0; kk < KG; ++kk) acc[r][kk] = 0.f;

    const float* Wb = W + (size_t)n0 * (KO * IN) + (size_t)(k0 * OUT + o) * IN;

    for (int nl = 0; nl < NC; ++nl) {
        const float* Wn = Wb + (size_t)nl * (KO * IN);
        float4 w[KG][2];
#pragma unroll
        for (int kk = 0; kk < KG; ++kk) {
            w[kk][0] = *(const float4*)(Wn + kk * (OUT * IN));
            w[kk][1] = *(const float4*)(Wn + kk * (OUT * IN) + 4);
        }
        float4 xr[4][2];
#pragma unroll
        for (int r = 0; r < 4; ++r) {
            xr[r][0] = *(const float4*)(&xs[grp + r][nl * IN]);
            xr[r][1] = *(const float4*)(&xs[grp + r][nl * IN + 4]);
        }
        float cw[KG];
#pragma unroll
        for (int kk = 0; kk < KG; ++kk) cw[kk] = c ? cs[nl][kk] : 0.1f;

#pragma unroll
        for (int kk = 0; kk < KG; ++kk) {
#pragma unroll
            for (int r = 0; r < 4; ++r) {
                float d = w[kk][0].x * xr[r][0].x + w[kk][0].y * xr[r][0].y
                        + w[kk][0].z * xr[r][0].z + w[kk][0].w * xr[r][0].w
                        + w[kk][1].x * xr[r][1].x + w[kk][1].y * xr[r][1].y
                        + w[kk][1].z * xr[r][1].z + w[kk][1].w * xr[r][1].w;
                acc[r][kk] += cw[kk] * d;
            }
        }
    }

#pragma unroll
    for (int r = 0; r < 4; ++r) {
        float* sp = s + (size_t)(b0 + grp + r) * KO + (size_t)k0 * OUT + o;
#pragma unroll
        for (int kk = 0; kk < KG; ++kk)
            atomicAdd(sp + kk * OUT, acc[r][kk]);   // 16 lanes = one 64B line
    }
}

// ---------------- squash s -> v (+out), and self-zero s for the next accumulation
__global__ __launch_bounds__(256) void k_squash(
    float* __restrict__ s, float* __restrict__ v, float* __restrict__ out)
{
    const int e = blockIdx.x * 256 + threadIdx.x;   // 0..40959
    float sv = s[e];
    s[e] = 0.f;
    float vv = sv * fabsf(sv) / (1.f + sv * sv);
    v[e] = vv;
    if (out) out[e] = vv;
}

// ---------------- a-pass, b-major (same structure as k_s): for each unit's 16 b x 12 n x 5 k:
// p(nl,kk) = sum_{b in tile, o} (W[n,k,o,:].x[b,n,:]) * v[b,k,o]; atomicAdd bij[n][k] += p/B
__global__ __launch_bounds__(64, 4) void k_a_atomic(
    const float* __restrict__ x, const float* __restrict__ W,
    const float* __restrict__ v, float* __restrict__ bij)
{
    __shared__ float xs[MB][XSTR];      // 6.25 KB
    __shared__ float vs[MB][84];        // 16 x 80(+4) floats = 5.25 KB (k-half of v rows)

    const int tid = threadIdx.x;
    const int id  = blockIdx.x;
    const int g   = id & 7;
    const int q   = id >> 3;
    const int bt  = q & 15;
    const int kg  = (q >> 4) & 1;
    const int chl = q >> 5;
    const int ch  = g * 12 + chl;
    const int b0  = bt * MB;
    const int n0  = ch * NC;
    const int k0  = kg * KG;

    for (int idx = tid; idx < MB * (NC * 2); idx += 64) {
        int bl = idx / (NC * 2), r = idx - bl * (NC * 2);
        float4 val = *(const float4*)(x + (size_t)(b0 + bl) * (N * IN) + (size_t)n0 * IN + r * 4);
        *(float4*)(&xs[bl][r * 4]) = val;
    }
    for (int idx = tid; idx < MB * (KG * 4); idx += 64) {   // 16 rows x 20 float4
        int bl = idx / (KG * 4), r = idx - bl * (KG * 4);
        float4 val = *(const float4*)(v + (size_t)(b0 + bl) * KO + (size_t)k0 * OUT + r * 4);
        *(float4*)(&vs[bl][r * 4]) = val;
    }
    __syncthreads();

    const int o   = tid & 15;
    const int grp = (tid >> 4) * 4;

    const float* Wb = W + (size_t)n0 * (KO * IN) + (size_t)(k0 * OUT + o) * IN;

    for (int nl = 0; nl < NC; ++nl) {
        const float* Wn = Wb + (size_t)nl * (KO * IN);
        float4 w[KG][2];
#pragma unroll
        for (int kk = 0; kk < KG; ++kk) {
            w[kk][0] = *(const float4*)(Wn + kk * (OUT * IN));
            w[kk][1] = *(const float4*)(Wn + kk * (OUT * IN) + 4);
        }
        float4 xr[4][2];
#pragma unroll
        for (int r = 0; r < 4; ++r) {
            xr[r][0] = *(const float4*)(&xs[grp + r][nl * IN]);
            xr[r][1] = *(const float4*)(&xs[grp + r][nl * IN + 4]);
        }
#pragma unroll
        for (int kk = 0; kk < KG; ++kk) {
            float p = 0.f;
#pragma unroll
            for (int r = 0; r < 4; ++r) {
                float d = w[kk][0].x * xr[r][0].x + w[kk][0].y * xr[r][0].y
                        + w[kk][0].z * xr[r][0].z + w[kk][0].w * xr[r][0].w
                        + w[kk][1].x * xr[r][1].x + w[kk][1].y * xr[r][1].y
                        + w[kk][1].z * xr[r][1].z + w[kk][1].w * xr[r][1].w;
                p += d * vs[grp + r][kk * OUT + o];
            }
            // reduce over 16 o-lanes, then over 4 groups (full-wave butterfly)
            p += __shfl_xor(p, 1);
            p += __shfl_xor(p, 2);
            p += __shfl_xor(p, 4);
            p += __shfl_xor(p, 8);
            p += __shfl_xor(p, 16);
            p += __shfl_xor(p, 32);
            if (tid == 0)
                atomicAdd(bij + (size_t)(n0 + nl) * C_ + (k0 + kk), p * (1.0f / B));
        }
    }
}

// ---------------- softmax over k (10) per n
__global__ __launch_bounds__(256) void k_softmax(
    const float* __restrict__ bij, float* __restrict__ c)
{
    int n = blockIdx.x * 256 + threadIdx.x;
    if (n >= N) return;
    float b[C_], m = -1e30f;
#pragma unroll
    for (int k = 0; k < C_; ++k) { b[k] = bij[(size_t)n * C_ + k]; m = fmaxf(m, b[k]); }
    float s = 0.f;
#pragma unroll
    for (int k = 0; k < C_; ++k) { float e = __expf(b[k] - m); b[k] = e; s += e; }
    float inv = 1.f / s;
#pragma unroll
    for (int k = 0; k < C_; ++k) c[(size_t)n * C_ + k] = b[k] * inv;
}

extern "C" void kernel_launch(void* const* d_in, const int* in_sizes, int n_in,
                              void* d_out, int out_size, void* d_ws, size_t ws_size,
                              hipStream_t stream)
{
    const float* x = (const float*)d_in[0];   // [B, N, IN]
    const float* W = (const float*)d_in[1];   // [1, N, C, OUT, IN]
    float* out = (float*)d_out;               // [B, C, OUT, 1] = 40960 floats
    float* ws  = (float*)d_ws;

    float* s    = ws;                         // 40960 (atomic accumulator)
    float* bij  = ws + 40960;                 // 11520 (atomic accumulator)
    float* c    = bij + 11520;                // 11520
    float* v    = c + 11520;                  // 40960

    // zero both atomic accumulators (contiguous) once per call
    hipMemsetAsync(ws, 0, (40960 + 11520) * sizeof(float), stream);

    const int GS = 3072;                      // 8 XCD * 12 chl * 2 kg * 16 bt

    // iteration 0: c = 1/C exactly (softmax of zeros)
    k_s_partial<<<GS, 64, 0, stream>>>(x, W, nullptr, s);
    k_squash<<<160, 256, 0, stream>>>(s, v, nullptr);
    k_a_atomic<<<GS, 64, 0, stream>>>(x, W, v, bij);
    k_softmax<<<5, 256, 0, stream>>>(bij, c);

    // iteration 1
    k_s_partial<<<GS, 64, 0, stream>>>(x, W, c, s);
    k_squash<<<160, 256, 0, stream>>>(s, v, nullptr);
    k_a_atomic<<<GS, 64, 0, stream>>>(x, W, v, bij);
    k_softmax<<<5, 256, 0, stream>>>(bij, c);

    // iteration 2 (final: write d_out)
    k_s_partial<<<GS, 64, 0, stream>>>(x, W, c, s);
    k_squash<<<160, 256, 0, stream>>>(s, v, out);
}

// Round 13
// 163.172 us; speedup vs baseline: 1.0486x; 1.0486x over previous
//
#include <hip/hip_runtime.h>
#include <math.h>

#define B 256
#define N 1152
#define C_ 10
#define OUT 16
#define IN 8
#define KO 160          // C_*OUT

// ---- unified geometry: 64-thread (1-wave) blocks, BT=4 rows/thread, KG=5 x 2 kg
#define MB 16           // batch rows per block
#define NC 12           // n per chunk
#define NCH 96          // N/NC -> slab 15.7 MB (< 21 MB L2-safe bound from R9)
#define KG 5
#define XSTR 100        // NC*8+4 padded x row stride

// ---------------- s-partial (R11-proven slab version, NC=12 geometry)
// partial[ch][b][k*16+o] = sum_{n in chunk} c[n,k]*(W[n,k,o,:].x[b,n,:])
// grid 3072 = 8 XCD * 12 chl * 2 kg * 16 bt (bt fastest -> W chunk L2-shared)
__global__ __launch_bounds__(64, 4) void k_s_partial(
    const float* __restrict__ x, const float* __restrict__ W,
    const float* __restrict__ c, float* __restrict__ partial)
{
    __shared__ float xs[MB][XSTR];
    __shared__ float cs[NC][KG];

    const int tid = threadIdx.x;
    const int id  = blockIdx.x;
    const int g   = id & 7;
    const int q   = id >> 3;
    const int bt  = q & 15;
    const int kg  = (q >> 4) & 1;
    const int chl = q >> 5;
    const int ch  = g * 12 + chl;
    const int b0  = bt * MB;
    const int n0  = ch * NC;
    const int k0  = kg * KG;

    for (int idx = tid; idx < MB * (NC * 2); idx += 64) {
        int bl = idx / (NC * 2), r = idx - bl * (NC * 2);
        float4 val = *(const float4*)(x + (size_t)(b0 + bl) * (N * IN) + (size_t)n0 * IN + r * 4);
        *(float4*)(&xs[bl][r * 4]) = val;
    }
    if (c) {
        for (int idx = tid; idx < NC * KG; idx += 64) {
            int nl = idx / KG, kk = idx - nl * KG;
            cs[nl][kk] = c[(size_t)(n0 + nl) * C_ + (k0 + kk)];
        }
    }
    __syncthreads();

    const int o   = tid & 15;
    const int grp = (tid >> 4) * 4;

    float acc[4][KG];
#pragma unroll
    for (int r = 0; r < 4; ++r)
#pragma unroll
        for (int kk = 0; kk < KG; ++kk) acc[r][kk] = 0.f;

    const float* Wb = W + (size_t)n0 * (KO * IN) + (size_t)(k0 * OUT + o) * IN;

    for (int nl = 0; nl < NC; ++nl) {
        const float* Wn = Wb + (size_t)nl * (KO * IN);
        float4 w[KG][2];
#pragma unroll
        for (int kk = 0; kk < KG; ++kk) {
            w[kk][0] = *(const float4*)(Wn + kk * (OUT * IN));
            w[kk][1] = *(const float4*)(Wn + kk * (OUT * IN) + 4);
        }
        float4 xr[4][2];
#pragma unroll
        for (int r = 0; r < 4; ++r) {
            xr[r][0] = *(const float4*)(&xs[grp + r][nl * IN]);
            xr[r][1] = *(const float4*)(&xs[grp + r][nl * IN + 4]);
        }
        float cw[KG];
#pragma unroll
        for (int kk = 0; kk < KG; ++kk) cw[kk] = c ? cs[nl][kk] : 0.1f;

#pragma unroll
        for (int kk = 0; kk < KG; ++kk) {
#pragma unroll
            for (int r = 0; r < 4; ++r) {
                float d = w[kk][0].x * xr[r][0].x + w[kk][0].y * xr[r][0].y
                        + w[kk][0].z * xr[r][0].z + w[kk][0].w * xr[r][0].w
                        + w[kk][1].x * xr[r][1].x + w[kk][1].y * xr[r][1].y
                        + w[kk][1].z * xr[r][1].z + w[kk][1].w * xr[r][1].w;
                acc[r][kk] += cw[kk] * d;
            }
        }
    }

#pragma unroll
    for (int r = 0; r < 4; ++r) {
        float* pp = partial + (size_t)ch * (B * KO) + (size_t)(b0 + grp + r) * KO
                  + (size_t)k0 * OUT + o;
#pragma unroll
        for (int kk = 0; kk < KG; ++kk) pp[kk * OUT] = acc[r][kk];
    }
}

// ---------------- reduce partials over 96 chunks + squash
__global__ __launch_bounds__(256) void k_reduce_squash(
    const float* __restrict__ partial, float* __restrict__ v, float* __restrict__ out)
{
    __shared__ float red[256];
    const int tid = threadIdx.x;
    const int e   = blockIdx.x * 64 + (tid & 63);
    const int q   = tid >> 6;
    float s = 0.f;
#pragma unroll
    for (int i = 0; i < NCH / 4; ++i)
        s += partial[(size_t)(q * (NCH / 4) + i) * (B * KO) + e];
    red[tid] = s;
    __syncthreads();
    if (q == 0) {
        s = red[tid] + red[tid + 64] + red[tid + 128] + red[tid + 192];
        float vv = s * fabsf(s) / (1.f + s * s);
        v[e] = vv;
        if (out) out[e] = vv;
    }
}

// ---------------- a-partial, b-major: pa[bt*4+grp][n][k] = sum_{4 b-rows, o} (W.x)*v
// Fix vs R12: v preloaded to 20 regs (no inner LDS reads); p[5] computed together, then
// 5 INTERLEAVED 4-level o-butterflies (independent streams pipeline; R12 had 60 serial
// 6-deep chains); 5 lanes store in parallel; grp-reduction deferred to k_bij (64 slices).
__global__ __launch_bounds__(64, 4) void k_a_partial(
    const float* __restrict__ x, const float* __restrict__ W,
    const float* __restrict__ v, float* __restrict__ pa)
{
    __shared__ float xs[MB][XSTR];

    const int tid = threadIdx.x;
    const int id  = blockIdx.x;
    const int g   = id & 7;
    const int q   = id >> 3;
    const int bt  = q & 15;
    const int kg  = (q >> 4) & 1;
    const int chl = q >> 5;
    const int ch  = g * 12 + chl;
    const int b0  = bt * MB;
    const int n0  = ch * NC;
    const int k0  = kg * KG;

    for (int idx = tid; idx < MB * (NC * 2); idx += 64) {
        int bl = idx / (NC * 2), r = idx - bl * (NC * 2);
        float4 val = *(const float4*)(x + (size_t)(b0 + bl) * (N * IN) + (size_t)n0 * IN + r * 4);
        *(float4*)(&xs[bl][r * 4]) = val;
    }
    __syncthreads();

    const int o   = tid & 15;
    const int grp = (tid >> 4) * 4;     // rows grp..grp+3

    // preload v values: vv[r][kk] = v[b0+grp+r][ (k0+kk)*16 + o ]  (coalesced 64B lines)
    float vv[4][KG];
#pragma unroll
    for (int r = 0; r < 4; ++r) {
        const float* vb = v + (size_t)(b0 + grp + r) * KO + (size_t)k0 * OUT + o;
#pragma unroll
        for (int kk = 0; kk < KG; ++kk) vv[r][kk] = vb[kk * OUT];
    }

    const float* Wb = W + (size_t)n0 * (KO * IN) + (size_t)(k0 * OUT + o) * IN;
    const size_t pa_base = (size_t)(bt * 4 + (tid >> 4)) * (N * C_);

    for (int nl = 0; nl < NC; ++nl) {
        const float* Wn = Wb + (size_t)nl * (KO * IN);
        float4 w[KG][2];
#pragma unroll
        for (int kk = 0; kk < KG; ++kk) {
            w[kk][0] = *(const float4*)(Wn + kk * (OUT * IN));
            w[kk][1] = *(const float4*)(Wn + kk * (OUT * IN) + 4);
        }
        float4 xr[4][2];
#pragma unroll
        for (int r = 0; r < 4; ++r) {
            xr[r][0] = *(const float4*)(&xs[grp + r][nl * IN]);
            xr[r][1] = *(const float4*)(&xs[grp + r][nl * IN + 4]);
        }

        float p[KG];
#pragma unroll
        for (int kk = 0; kk < KG; ++kk) p[kk] = 0.f;
#pragma unroll
        for (int kk = 0; kk < KG; ++kk) {
#pragma unroll
            for (int r = 0; r < 4; ++r) {
                float d = w[kk][0].x * xr[r][0].x + w[kk][0].y * xr[r][0].y
                        + w[kk][0].z * xr[r][0].z + w[kk][0].w * xr[r][0].w
                        + w[kk][1].x * xr[r][1].x + w[kk][1].y * xr[r][1].y
                        + w[kk][1].z * xr[r][1].z + w[kk][1].w * xr[r][1].w;
                p[kk] += d * vv[r][kk];
            }
        }
        // 5 interleaved 4-level butterflies over the 16 o-lanes
#pragma unroll
        for (int lv = 1; lv <= 8; lv <<= 1) {
#pragma unroll
            for (int kk = 0; kk < KG; ++kk) p[kk] += __shfl_xor(p[kk], lv);
        }
        // 5 lanes store in parallel (all 16 o-lanes hold identical sums)
        float* pp = pa + pa_base + (size_t)(n0 + nl) * C_ + k0;
#pragma unroll
        for (int kk = 0; kk < KG; ++kk)
            if (o == kk) pp[kk] = p[kk];
    }
}

// ---------------- bij update: sum pa over 64 slices (coalesced); 45 x 256 = 11520 threads
__global__ __launch_bounds__(256) void k_bij(
    const float* __restrict__ pa, float* __restrict__ bij, int accumulate)
{
    const int e = blockIdx.x * 256 + threadIdx.x;   // exactly 11520
    float a = 0.f;
#pragma unroll
    for (int j = 0; j < 64; ++j)
        a += pa[(size_t)j * (N * C_) + e];
    a *= (1.0f / B);
    bij[e] = accumulate ? (bij[e] + a) : a;
}

// ---------------- softmax over k (10) per n
__global__ __launch_bounds__(256) void k_softmax(
    const float* __restrict__ bij, float* __restrict__ c)
{
    int n = blockIdx.x * 256 + threadIdx.x;
    if (n >= N) return;
    float b[C_], m = -1e30f;
#pragma unroll
    for (int k = 0; k < C_; ++k) { b[k] = bij[(size_t)n * C_ + k]; m = fmaxf(m, b[k]); }
    float s = 0.f;
#pragma unroll
    for (int k = 0; k < C_; ++k) { float e = __expf(b[k] - m); b[k] = e; s += e; }
    float inv = 1.f / s;
#pragma unroll
    for (int k = 0; k < C_; ++k) c[(size_t)n * C_ + k] = b[k] * inv;
}

extern "C" void kernel_launch(void* const* d_in, const int* in_sizes, int n_in,
                              void* d_out, int out_size, void* d_ws, size_t ws_size,
                              hipStream_t stream)
{
    const float* x = (const float*)d_in[0];   // [B, N, IN]
    const float* W = (const float*)d_in[1];   // [1, N, C, OUT, IN]
    float* out = (float*)d_out;               // [B, C, OUT, 1] = 40960 floats
    float* ws  = (float*)d_ws;

    float* part = ws;                         // 96 * 40960 = 3932160 floats (15.7 MB)
    float* pa   = ws + 3932160;               // 64 * 11520 = 737280
    float* bij  = pa + 737280;                // 11520
    float* c    = bij + 11520;                // 11520
    float* v    = c + 11520;                  // 40960

    const int GS = 3072;                      // 8 XCD * 12 chl * 2 kg * 16 bt

    // iteration 0: c = 1/C exactly (softmax of zeros)
    k_s_partial<<<GS, 64, 0, stream>>>(x, W, nullptr, part);
    k_reduce_squash<<<640, 256, 0, stream>>>(part, v, nullptr);
    k_a_partial<<<GS, 64, 0, stream>>>(x, W, v, pa);
    k_bij<<<45, 256, 0, stream>>>(pa, bij, 0);
    k_softmax<<<5, 256, 0, stream>>>(bij, c);

    // iteration 1
    k_s_partial<<<GS, 64, 0, stream>>>(x, W, c, part);
    k_reduce_squash<<<640, 256, 0, stream>>>(part, v, nullptr);
    k_a_partial<<<GS, 64, 0, stream>>>(x, W, v, pa);
    k_bij<<<45, 256, 0, stream>>>(pa, bij, 1);
    k_softmax<<<5, 256, 0, stream>>>(bij, c);

    // iteration 2 (final: write d_out)
    k_s_partial<<<GS, 64, 0, stream>>>(x, W, c, part);
    k_reduce_squash<<<640, 256, 0, stream>>>(part, v, out);
}